// Round 4
// baseline (2744.663 us; speedup 1.0000x reference)
//
#include <hip/hip_runtime.h>

typedef unsigned short u16;

// ---- problem constants ----
#define BB 256
#define LL 200
#define NN 512
#define DD 64
#define HH 128

// d_out element offsets (fp32 elements)
#define MU_OFF   26214400
#define LV_OFF   26230784
#define ZT_OFF   26247168
#define ZD_OFF   29523968

__device__ __forceinline__ float bf2f(u16 u) {
    union { unsigned int i; float f; } v; v.i = ((unsigned int)u) << 16; return v.f;
}
// Runtime input-dtype probe: tvec[199] as bf16 reads ~1.99 if inputs are
// bf16; if fp32, u16[199] is the high half of float tvec[99] (~0.988).
__device__ __forceinline__ bool detect_f32(const void* tvec) {
    float v = bf2f(((const u16*)tvec)[199]);
    return !(v > 1.5f && v < 2.5f);
}
__device__ __forceinline__ float loadf(const void* p, long idx, bool f32m) {
    return f32m ? ((const float*)p)[idx] : bf2f(((const u16*)p)[idx]);
}

// ---------------------------------------------------------------------------
// Kernel 1: encoder. 2 batch rows per block, 512 threads, fp32 VALU.
// Writes mu/logvar (fp32 out) and z0 (fp32, ws).
// ---------------------------------------------------------------------------
__global__ __launch_bounds__(512) void enc_kernel(
    const void* __restrict__ x_seq, const void* __restrict__ tvec,
    const void* __restrict__ epsp,
    const void* __restrict__ ew1, const void* __restrict__ eb1,
    const void* __restrict__ ew2, const void* __restrict__ eb2,
    const void* __restrict__ ew3, const void* __restrict__ eb3,
    const void* __restrict__ muw, const void* __restrict__ mub,
    const void* __restrict__ lvw, const void* __restrict__ lvb,
    float* __restrict__ out, float* __restrict__ z0f)
{
    __shared__ __align__(16) float xs[2][512];
    __shared__ __align__(16) float h1[2][512];
    __shared__ __align__(16) float h2[2][256];
    __shared__ __align__(16) float h3[2][128];
    __shared__ float muv[2][64], lvv[2][64];
    const bool m = detect_f32(tvec);
    const int t = threadIdx.x;
    const int b0 = blockIdx.x * 2;

    xs[0][t] = loadf(x_seq, (long)(b0 + 0) * 102400 + t, m);
    xs[1][t] = loadf(x_seq, (long)(b0 + 1) * 102400 + t, m);
    __syncthreads();

    // L1: 512 -> 512, one neuron per thread
    {
        float a0 = 0.f, a1 = 0.f;
        const float4* x0v = (const float4*)xs[0];
        const float4* x1v = (const float4*)xs[1];
        #pragma unroll 4
        for (int j4 = 0; j4 < 128; ++j4) {
            float4 xa = x0v[j4], xb = x1v[j4];
            float w0 = loadf(ew1, (4 * j4 + 0) * 512 + t, m);
            float w1v = loadf(ew1, (4 * j4 + 1) * 512 + t, m);
            float w2v = loadf(ew1, (4 * j4 + 2) * 512 + t, m);
            float w3v = loadf(ew1, (4 * j4 + 3) * 512 + t, m);
            a0 += xa.x * w0 + xa.y * w1v + xa.z * w2v + xa.w * w3v;
            a1 += xb.x * w0 + xb.y * w1v + xb.z * w2v + xb.w * w3v;
        }
        float bb = loadf(eb1, t, m);
        h1[0][t] = fmaxf(a0 + bb, 0.f);
        h1[1][t] = fmaxf(a1 + bb, 0.f);
    }
    __syncthreads();

    // L2: 512 -> 256, 2 threads per neuron
    {
        const int i = t >> 1, s = t & 1;
        float a0 = 0.f, a1 = 0.f;
        const float4* p0 = (const float4*)&h1[0][s * 256];
        const float4* p1 = (const float4*)&h1[1][s * 256];
        #pragma unroll 4
        for (int j4 = 0; j4 < 64; ++j4) {
            float4 xa = p0[j4], xb = p1[j4];
            int j = s * 256 + 4 * j4;
            float w0 = loadf(ew2, (j + 0) * 256 + i, m);
            float w1v = loadf(ew2, (j + 1) * 256 + i, m);
            float w2v = loadf(ew2, (j + 2) * 256 + i, m);
            float w3v = loadf(ew2, (j + 3) * 256 + i, m);
            a0 += xa.x * w0 + xa.y * w1v + xa.z * w2v + xa.w * w3v;
            a1 += xb.x * w0 + xb.y * w1v + xb.z * w2v + xb.w * w3v;
        }
        a0 += __shfl_xor(a0, 1);
        a1 += __shfl_xor(a1, 1);
        if (s == 0) {
            float bb = loadf(eb2, i, m);
            h2[0][i] = fmaxf(a0 + bb, 0.f);
            h2[1][i] = fmaxf(a1 + bb, 0.f);
        }
    }
    __syncthreads();

    // L3: 256 -> 128, 4 threads per neuron
    {
        const int i = t >> 2, s = t & 3;
        float a0 = 0.f, a1 = 0.f;
        const float4* p0 = (const float4*)&h2[0][s * 64];
        const float4* p1 = (const float4*)&h2[1][s * 64];
        #pragma unroll 4
        for (int j4 = 0; j4 < 16; ++j4) {
            float4 xa = p0[j4], xb = p1[j4];
            int j = s * 64 + 4 * j4;
            float w0 = loadf(ew3, (j + 0) * 128 + i, m);
            float w1v = loadf(ew3, (j + 1) * 128 + i, m);
            float w2v = loadf(ew3, (j + 2) * 128 + i, m);
            float w3v = loadf(ew3, (j + 3) * 128 + i, m);
            a0 += xa.x * w0 + xa.y * w1v + xa.z * w2v + xa.w * w3v;
            a1 += xb.x * w0 + xb.y * w1v + xb.z * w2v + xb.w * w3v;
        }
        a0 += __shfl_xor(a0, 1); a0 += __shfl_xor(a0, 2);
        a1 += __shfl_xor(a1, 1); a1 += __shfl_xor(a1, 2);
        if (s == 0) {
            float bb = loadf(eb3, i, m);
            h3[0][i] = fmaxf(a0 + bb, 0.f);
            h3[1][i] = fmaxf(a1 + bb, 0.f);
        }
    }
    __syncthreads();

    // mu / logvar heads: 128 -> 64 each
    {
        const int o = t >> 2, s = t & 3;
        const void* wp; const void* bp; int oc;
        if (o < 64) { wp = muw; bp = mub; oc = o; }
        else        { wp = lvw; bp = lvb; oc = o - 64; }
        float a0 = 0.f, a1 = 0.f;
        const float4* p0 = (const float4*)&h3[0][s * 32];
        const float4* p1 = (const float4*)&h3[1][s * 32];
        #pragma unroll
        for (int j4 = 0; j4 < 8; ++j4) {
            float4 xa = p0[j4], xb = p1[j4];
            int j = s * 32 + 4 * j4;
            float w0 = loadf(wp, (j + 0) * 64 + oc, m);
            float w1v = loadf(wp, (j + 1) * 64 + oc, m);
            float w2v = loadf(wp, (j + 2) * 64 + oc, m);
            float w3v = loadf(wp, (j + 3) * 64 + oc, m);
            a0 += xa.x * w0 + xa.y * w1v + xa.z * w2v + xa.w * w3v;
            a1 += xb.x * w0 + xb.y * w1v + xb.z * w2v + xb.w * w3v;
        }
        a0 += __shfl_xor(a0, 1); a0 += __shfl_xor(a0, 2);
        a1 += __shfl_xor(a1, 1); a1 += __shfl_xor(a1, 2);
        if (s == 0) {
            float bb = loadf(bp, oc, m);
            if (o < 64) { muv[0][oc] = a0 + bb; muv[1][oc] = a1 + bb; }
            else        { lvv[0][oc] = a0 + bb; lvv[1][oc] = a1 + bb; }
        }
    }
    __syncthreads();

    if (t < 128) {
        int r = t >> 6, d = t & 63;
        float mm = muv[r][d], l = lvv[r][d];
        float z = mm + expf(0.5f * l) * loadf(epsp, (b0 + r) * 64 + d, m);
        z0f[(b0 + r) * 64 + d] = z;
        out[MU_OFF + (b0 + r) * 64 + d] = mm;
        out[LV_OFF + (b0 + r) * 64 + d] = l;
    }
}

// ---------------------------------------------------------------------------
// Kernel 2: ODE RK4 integrator. One block per batch row; 199 steps in-kernel.
// fp32 weights in registers; two-pass LN; fp32 outputs.
// zdiff computed as (z_next - z)/dt exactly like the reference.
// ---------------------------------------------------------------------------
__global__ __launch_bounds__(512) void ode_kernel(
    const void* __restrict__ tvec,
    const void* __restrict__ w1, const void* __restrict__ b1,
    const void* __restrict__ w2, const void* __restrict__ b2,
    const void* __restrict__ w3, const void* __restrict__ b3,
    const void* __restrict__ lng, const void* __restrict__ lnb,
    const float* __restrict__ z0f,
    float* __restrict__ zt_out, float* __restrict__ zd_out)
{
    __shared__ __align__(16) float zc[64];
    __shared__ __align__(16) float h1f[128];
    __shared__ __align__(16) float h2f[128];
    __shared__ float dzf[64];
    __shared__ float dts[200];

    const bool mdt = detect_f32(tvec);
    const int t = threadIdx.x;
    const int b = blockIdx.x;
    const int i1 = t >> 2, s1 = t & 3;
    const int i3 = t >> 3, s3 = t & 7;

    float w1r[16], w2r[32], w3r[16];
    #pragma unroll
    for (int jj = 0; jj < 16; ++jj)
        w1r[jj] = loadf(w1, (16 * s1 + jj) * 128 + i1, mdt);
    #pragma unroll
    for (int jq = 0; jq < 8; ++jq) {
        int base = 32 * s1 + ((4 * jq + 8 * s1) & 31);   // rotation kills bank conflicts
        #pragma unroll
        for (int q = 0; q < 4; ++q)
            w2r[jq * 4 + q] = loadf(w2, (base + q) * 128 + i1, mdt);
    }
    #pragma unroll
    for (int jq = 0; jq < 4; ++jq) {
        int base = 16 * s3 + ((4 * jq + 4 * s3) & 15);
        #pragma unroll
        for (int q = 0; q < 4; ++q)
            w3r[jq * 4 + q] = loadf(w3, (base + q) * 64 + i3, mdt);
    }
    const float bias1 = (s1 == 0) ? loadf(b1, i1, mdt) : 0.f;
    const float bias2 = (s1 == 0) ? loadf(b2, i1, mdt) : 0.f;
    const float bias3 = (s3 == 0) ? loadf(b3, i3, mdt) : 0.f;
    float g_ln = 0.f, b_ln = 0.f, zbr = 0.f, kar = 0.f;
    if (t < 64) {
        g_ln = loadf(lng, t, mdt); b_ln = loadf(lnb, t, mdt);
        zbr = z0f[b * 64 + t];
        zc[t] = zbr;
        zt_out[b * 12800 + t] = zbr;
    }
    if (t < 199) dts[t] = loadf(tvec, t + 1, mdt) - loadf(tvec, t, mdt);
    __syncthreads();

    #pragma unroll 1
    for (int step = 0; step < 199; ++step) {
        const float h = dts[step];
        #pragma unroll
        for (int e = 0; e < 4; ++e) {
            // layer1: h1 = silu(z @ W1 + b1)
            float a = 0.f;
            #pragma unroll
            for (int jq = 0; jq < 4; ++jq) {
                float4 zv = *(const float4*)&zc[16 * s1 + 4 * jq];
                a += zv.x * w1r[4 * jq + 0] + zv.y * w1r[4 * jq + 1]
                   + zv.z * w1r[4 * jq + 2] + zv.w * w1r[4 * jq + 3];
            }
            a += __shfl_xor(a, 1); a += __shfl_xor(a, 2);
            if (s1 == 0) { float v = a + bias1; h1f[i1] = v / (1.f + expf(-v)); }
            __syncthreads();

            // layer2: h2 = silu(h1 @ W2 + b2)
            a = 0.f;
            #pragma unroll
            for (int jq = 0; jq < 8; ++jq) {
                int idx = 32 * s1 + ((4 * jq + 8 * s1) & 31);
                float4 hv = *(const float4*)&h1f[idx];
                a += hv.x * w2r[4 * jq + 0] + hv.y * w2r[4 * jq + 1]
                   + hv.z * w2r[4 * jq + 2] + hv.w * w2r[4 * jq + 3];
            }
            a += __shfl_xor(a, 1); a += __shfl_xor(a, 2);
            if (s1 == 0) { float v = a + bias2; h2f[i1] = v / (1.f + expf(-v)); }
            __syncthreads();

            // layer3: dz = h2 @ W3 + b3
            a = 0.f;
            #pragma unroll
            for (int jq = 0; jq < 4; ++jq) {
                int idx = 16 * s3 + ((4 * jq + 4 * s3) & 15);
                float4 hv = *(const float4*)&h2f[idx];
                a += hv.x * w3r[4 * jq + 0] + hv.y * w3r[4 * jq + 1]
                   + hv.z * w3r[4 * jq + 2] + hv.w * w3r[4 * jq + 3];
            }
            a += __shfl_xor(a, 1); a += __shfl_xor(a, 2); a += __shfl_xor(a, 4);
            if (s3 == 0) dzf[i3] = a + bias3;
            __syncthreads();

            // layernorm (two-pass, mirrors reference) + RK4 bookkeeping
            if (t < 64) {
                float v = dzf[t];
                float sm = v;
                #pragma unroll
                for (int mm = 1; mm < 64; mm <<= 1) sm += __shfl_xor(sm, mm);
                float mean = sm * (1.f / 64.f);
                float d = v - mean;
                float sq = d * d;
                #pragma unroll
                for (int mm = 1; mm < 64; mm <<= 1) sq += __shfl_xor(sq, mm);
                float var = sq * (1.f / 64.f);
                float y = d / sqrtf(var + 1e-5f) * g_ln + b_ln;
                if (e == 0)      { kar = y;          zc[t] = zbr + 0.5f * h * y; }
                else if (e == 1) { kar += 2.f * y;   zc[t] = zbr + 0.5f * h * y; }
                else if (e == 2) { kar += 2.f * y;   zc[t] = zbr + h * y; }
                else {
                    kar += y;
                    float zn = zbr + (h * (1.f / 6.f)) * kar;
                    zt_out[b * 12800 + (step + 1) * 64 + t] = zn;
                    zd_out[b * 12736 + step * 64 + t] = (zn - zbr) / h;  // as reference
                    zbr = zn; zc[t] = zn;
                }
            }
            __syncthreads();
        }
    }
}

// ---------------------------------------------------------------------------
// Kernel 3: decoder, fp32 VALU. 8 z-rows per block, 512 threads = one output
// neuron per thread. Reads fp32 z_traj (exact, like reference).
// ---------------------------------------------------------------------------
template<bool F32>
__device__ __forceinline__ float ldw(const void* p, int idx) {
    return F32 ? ((const float*)p)[idx] : bf2f(((const u16*)p)[idx]);
}

template<bool F32>
__device__ void dec_body(
    const float* __restrict__ zt,
    const void* __restrict__ w1, const void* __restrict__ b1,
    const void* __restrict__ w2, const void* __restrict__ b2,
    const void* __restrict__ w3, const void* __restrict__ b3,
    float* __restrict__ xhat)
{
    __shared__ __align__(16) float zs[8][64];
    __shared__ __align__(16) float g1[8][512];
    __shared__ __align__(16) float g2[8][512];
    const int t = threadIdx.x;
    const long r0 = (long)blockIdx.x * 8;
    {
        int r = t >> 6, k = t & 63;
        zs[r][k] = zt[(r0 + r) * 64 + k];
    }
    __syncthreads();

    float acc[8];
    // L1: 64 -> 512
    #pragma unroll
    for (int r = 0; r < 8; ++r) acc[r] = 0.f;
    #pragma unroll 4
    for (int k4 = 0; k4 < 16; ++k4) {
        float4 zv[8];
        #pragma unroll
        for (int r = 0; r < 8; ++r) zv[r] = *(const float4*)&zs[r][k4 * 4];
        #pragma unroll
        for (int q = 0; q < 4; ++q) {
            float w = ldw<F32>(w1, (k4 * 4 + q) * 512 + t);
            #pragma unroll
            for (int r = 0; r < 8; ++r) {
                float zq = (q == 0) ? zv[r].x : (q == 1) ? zv[r].y : (q == 2) ? zv[r].z : zv[r].w;
                acc[r] += zq * w;
            }
        }
    }
    {
        float bb = ldw<F32>(b1, t);
        #pragma unroll
        for (int r = 0; r < 8; ++r) g1[r][t] = fmaxf(acc[r] + bb, 0.f);
    }
    __syncthreads();

    // L2: 512 -> 512
    #pragma unroll
    for (int r = 0; r < 8; ++r) acc[r] = 0.f;
    #pragma unroll 2
    for (int k4 = 0; k4 < 128; ++k4) {
        float4 hv[8];
        #pragma unroll
        for (int r = 0; r < 8; ++r) hv[r] = *(const float4*)&g1[r][k4 * 4];
        #pragma unroll
        for (int q = 0; q < 4; ++q) {
            float w = ldw<F32>(w2, (k4 * 4 + q) * 512 + t);
            #pragma unroll
            for (int r = 0; r < 8; ++r) {
                float hq = (q == 0) ? hv[r].x : (q == 1) ? hv[r].y : (q == 2) ? hv[r].z : hv[r].w;
                acc[r] += hq * w;
            }
        }
    }
    {
        float bb = ldw<F32>(b2, t);
        #pragma unroll
        for (int r = 0; r < 8; ++r) g2[r][t] = fmaxf(acc[r] + bb, 0.f);
    }
    __syncthreads();

    // L3: 512 -> 512, no relu, write out
    #pragma unroll
    for (int r = 0; r < 8; ++r) acc[r] = 0.f;
    #pragma unroll 2
    for (int k4 = 0; k4 < 128; ++k4) {
        float4 hv[8];
        #pragma unroll
        for (int r = 0; r < 8; ++r) hv[r] = *(const float4*)&g2[r][k4 * 4];
        #pragma unroll
        for (int q = 0; q < 4; ++q) {
            float w = ldw<F32>(w3, (k4 * 4 + q) * 512 + t);
            #pragma unroll
            for (int r = 0; r < 8; ++r) {
                float hq = (q == 0) ? hv[r].x : (q == 1) ? hv[r].y : (q == 2) ? hv[r].z : hv[r].w;
                acc[r] += hq * w;
            }
        }
    }
    {
        float bb = ldw<F32>(b3, t);
        #pragma unroll
        for (int r = 0; r < 8; ++r)
            xhat[(r0 + r) * 512 + t] = acc[r] + bb;
    }
}

__global__ __launch_bounds__(512) void dec_kernel(
    const float* __restrict__ zt, const void* __restrict__ tvec,
    const void* __restrict__ w1, const void* __restrict__ b1,
    const void* __restrict__ w2, const void* __restrict__ b2,
    const void* __restrict__ w3, const void* __restrict__ b3,
    float* __restrict__ xhat)
{
    if (detect_f32(tvec))
        dec_body<true>(zt, w1, b1, w2, b2, w3, b3, xhat);
    else
        dec_body<false>(zt, w1, b1, w2, b2, w3, b3, xhat);
}

// ---------------------------------------------------------------------------
extern "C" void kernel_launch(void* const* d_in, const int* in_sizes, int n_in,
                              void* d_out, int out_size, void* d_ws, size_t ws_size,
                              hipStream_t stream)
{
    float* out = (float*)d_out;
    float* z0f = (float*)d_ws;   // 256*64 fp32 = 64 KB — only workspace use

    enc_kernel<<<128, 512, 0, stream>>>(
        d_in[0], d_in[1], d_in[2], d_in[3], d_in[4], d_in[5], d_in[6],
        d_in[7], d_in[8], d_in[9], d_in[10], d_in[11], d_in[12],
        out, z0f);

    ode_kernel<<<256, 512, 0, stream>>>(
        d_in[1], d_in[13], d_in[14], d_in[15], d_in[16],
        d_in[17], d_in[18], d_in[19], d_in[20], z0f,
        out + ZT_OFF, out + ZD_OFF);

    dec_kernel<<<6400, 512, 0, stream>>>(
        out + ZT_OFF, d_in[1], d_in[21], d_in[22], d_in[23], d_in[24],
        d_in[25], d_in[26], out);
}